// Round 1
// baseline (12797.282 us; speedup 1.0000x reference)
//
#include <hip/hip_runtime.h>

#define N_USERS  200000
#define N_ITEMS  100000
#define N_TOPICS 100
#define N_NODES  (N_USERS + N_ITEMS + N_TOPICS)
#define DIM      64

// HW fp32 atomic (global_atomic_add_f32). Plain atomicAdd may lower to a CAS
// loop when the compiler can't prove coarse-grained memory — fatal at ~1e9 ops.
__device__ __forceinline__ void atomic_add_f32(float* p, float v) {
    unsafeAtomicAdd(p, v);
}

// One edge handled by 16 lanes; each lane moves a float4 (coalesced 64B/16-lane
// segment on both gather and scatter sides).
__global__ void spmv_atomic_kernel(const int* __restrict__ rows,
                                   const int* __restrict__ cols,
                                   const float* __restrict__ vals,
                                   const float* __restrict__ h_src,
                                   float* __restrict__ h_dst,
                                   int n_edges) {
    long gid = (long)blockIdx.x * blockDim.x + threadIdx.x;
    int  e    = (int)(gid >> 4);
    int  lane = (int)(gid & 15);
    if (e >= n_edges) return;
    int   r = rows[e];
    int   c = cols[e];
    float v = vals[e];
    float4 s = ((const float4*)(h_src + (size_t)c * DIM))[lane];
    float* dst = h_dst + (size_t)r * DIM + lane * 4;
    atomic_add_f32(dst + 0, v * s.x);
    atomic_add_f32(dst + 1, v * s.y);
    atomic_add_f32(dst + 2, v * s.z);
    atomic_add_f32(dst + 3, v * s.w);
}

// Accumulate the batch rows of the current layer output into u_acc / it_acc.
// first=1 overwrites (ws is poisoned 0xAA before every timed call).
__global__ void gather_add_kernel(const float* __restrict__ h,
                                  const int* __restrict__ users,
                                  const int* __restrict__ items,
                                  float* __restrict__ u_acc,
                                  float* __restrict__ it_acc,
                                  int B, int first) {
    int gid  = blockIdx.x * blockDim.x + threadIdx.x;
    int b    = gid >> 4;
    int lane = gid & 15;
    if (b >= B) return;
    int u  = users[b];
    int it = N_USERS + items[b];
    float4 uv = ((const float4*)(h + (size_t)u  * DIM))[lane];
    float4 iv = ((const float4*)(h + (size_t)it * DIM))[lane];
    float4* up = (float4*)(u_acc  + (size_t)b * DIM) + lane;
    float4* ip = (float4*)(it_acc + (size_t)b * DIM) + lane;
    if (first) {
        *up = uv;
        *ip = iv;
    } else {
        float4 a = *up;
        a.x += uv.x; a.y += uv.y; a.z += uv.z; a.w += uv.w;
        *up = a;
        float4 c = *ip;
        c.x += iv.x; c.y += iv.y; c.z += iv.z; c.w += iv.w;
        *ip = c;
    }
}

// out[b] = dot64(u_acc[b], it_acc[b]) / 16  (the /(LAYERS+1) on both sides).
// Each b occupies exactly one 64-lane wave (block=256 => wave-aligned).
__global__ void dot_kernel(const float* __restrict__ u_acc,
                           const float* __restrict__ it_acc,
                           float* __restrict__ out, int B) {
    int gid  = blockIdx.x * blockDim.x + threadIdx.x;
    int b    = gid >> 6;
    int lane = gid & 63;
    if (b >= B) return;
    float p = u_acc[(size_t)b * DIM + lane] * it_acc[(size_t)b * DIM + lane];
    #pragma unroll
    for (int off = 32; off > 0; off >>= 1)
        p += __shfl_down(p, off, 64);
    if (lane == 0) out[b] = p * (1.0f / 16.0f);
}

extern "C" void kernel_launch(void* const* d_in, const int* in_sizes, int n_in,
                              void* d_out, int out_size, void* d_ws, size_t ws_size,
                              hipStream_t stream) {
    const int*   users = (const int*)d_in[0];
    const int*   items = (const int*)d_in[1];
    const int*   erows = (const int*)d_in[2];
    const int*   ecols = (const int*)d_in[3];
    const float* evals = (const float*)d_in[4];
    const float* uemb  = (const float*)d_in[5];
    const float* iemb  = (const float*)d_in[6];
    const float* temb  = (const float*)d_in[7];
    float* out = (float*)d_out;

    const int n_edges = in_sizes[2];
    const int B       = in_sizes[0];

    const size_t hbytes = (size_t)N_NODES * DIM * sizeof(float);   // 76.8 MB
    const size_t abytes = (size_t)B * DIM * sizeof(float);          // 4.2 MB
    char* ws = (char*)d_ws;
    float* hA     = (float*)(ws);
    float* hB     = (float*)(ws + hbytes);
    float* u_acc  = (float*)(ws + 2 * hbytes);
    float* it_acc = (float*)(ws + 2 * hbytes + abytes);

    // h0 = concat(user_emb, item_emb, topic_emb) -> hA
    hipMemcpyAsync(hA,                                   uemb, (size_t)N_USERS  * DIM * sizeof(float), hipMemcpyDeviceToDevice, stream);
    hipMemcpyAsync(hA + (size_t)N_USERS * DIM,           iemb, (size_t)N_ITEMS  * DIM * sizeof(float), hipMemcpyDeviceToDevice, stream);
    hipMemcpyAsync(hA + (size_t)(N_USERS + N_ITEMS) * DIM, temb, (size_t)N_TOPICS * DIM * sizeof(float), hipMemcpyDeviceToDevice, stream);

    dim3 blk(256);
    const int gblocks = (B * 16 + 255) / 256;
    gather_add_kernel<<<gblocks, blk, 0, stream>>>(hA, users, items, u_acc, it_acc, B, 1);

    const long nthreads = (long)n_edges * 16;
    const int  eblocks  = (int)((nthreads + 255) / 256);

    float* src = hA;
    float* dst = hB;
    for (int l = 0; l < 3; ++l) {
        hipMemsetAsync(dst, 0, hbytes, stream);
        spmv_atomic_kernel<<<eblocks, blk, 0, stream>>>(erows, ecols, evals, src, dst, n_edges);
        gather_add_kernel<<<gblocks, blk, 0, stream>>>(dst, users, items, u_acc, it_acc, B, 0);
        float* t = src; src = dst; dst = t;
    }

    dot_kernel<<<(B * 64 + 255) / 256, blk, 0, stream>>>(u_acc, it_acc, out, B);
}

// Round 2
// 2120.038 us; speedup vs baseline: 6.0363x; 6.0363x over previous
//
#include <hip/hip_runtime.h>

#define N_USERS  200000
#define N_ITEMS  100000
#define N_TOPICS 100
#define N_NODES  (N_USERS + N_ITEMS + N_TOPICS)
#define DIM      64
#define SCAN_T   1024

// ---------- CSR build ----------

__global__ void hist_kernel(const int* __restrict__ rows, int* __restrict__ cnt,
                            int n_edges) {
    int stride = gridDim.x * blockDim.x;
    for (int e = blockIdx.x * blockDim.x + threadIdx.x; e < n_edges; e += stride)
        atomicAdd(&cnt[rows[e]], 1);
}

// Single-block exclusive scan: thread t owns a contiguous chunk of rows.
__global__ void scan_kernel(const int* __restrict__ cnt, int* __restrict__ row_ptr,
                            int n) {
    __shared__ int sums[SCAN_T];
    int t  = threadIdx.x;
    int ch = (n + SCAN_T - 1) / SCAN_T;
    int s0 = t * ch;
    int s1 = min(n, s0 + ch);
    int s  = 0;
    for (int i = s0; i < s1; ++i) s += cnt[i];
    sums[t] = s;
    __syncthreads();
    for (int off = 1; off < SCAN_T; off <<= 1) {
        int v = (t >= off) ? sums[t - off] : 0;
        __syncthreads();
        sums[t] += v;
        __syncthreads();
    }
    int run = (t == 0) ? 0 : sums[t - 1];   // exclusive prefix of this chunk
    for (int i = s0; i < s1; ++i) { row_ptr[i] = run; run += cnt[i]; }
    if (t == SCAN_T - 1) row_ptr[n] = sums[SCAN_T - 1]; // total = n_edges
}

__global__ void scatter_kernel(const int* __restrict__ rows,
                               const int* __restrict__ cols,
                               const float* __restrict__ vals,
                               const int* __restrict__ row_ptr,
                               int* __restrict__ fill,
                               int* __restrict__ csr_col,
                               float* __restrict__ csr_val,
                               int n_edges) {
    int stride = gridDim.x * blockDim.x;
    for (int e = blockIdx.x * blockDim.x + threadIdx.x; e < n_edges; e += stride) {
        int r   = rows[e];
        int pos = row_ptr[r] + atomicAdd(&fill[r], 1);
        csr_col[pos] = cols[e];
        csr_val[pos] = vals[e];
    }
}

// ---------- SpMV: one 64-lane wave per row, lane = dim element ----------
__global__ void spmv_csr_kernel(const int* __restrict__ row_ptr,
                                const int* __restrict__ csr_col,
                                const float* __restrict__ csr_val,
                                const float* __restrict__ h_src,
                                float* __restrict__ h_dst) {
    int wid  = (int)(((long)blockIdx.x * blockDim.x + threadIdx.x) >> 6);
    int lane = threadIdx.x & 63;
    if (wid >= N_NODES) return;
    int p0 = row_ptr[wid];
    int p1 = row_ptr[wid + 1];
    float acc = 0.f;
    for (int base = p0; base < p1; base += 64) {
        int n = min(64, p1 - base);
        int   c = 0;
        float v = 0.f;
        if (lane < n) { c = csr_col[base + lane]; v = csr_val[base + lane]; }
        for (int j = 0; j < n; ++j) {
            int   cj = __shfl(c, j, 64);
            float vj = __shfl(v, j, 64);
            acc += vj * h_src[(size_t)cj * DIM + lane];
        }
    }
    h_dst[(size_t)wid * DIM + lane] = acc;
}

// ---------- batch-row accumulation + readout ----------

__global__ void gather_add_kernel(const float* __restrict__ h,
                                  const int* __restrict__ users,
                                  const int* __restrict__ items,
                                  float* __restrict__ u_acc,
                                  float* __restrict__ it_acc,
                                  int B, int first) {
    int gid  = blockIdx.x * blockDim.x + threadIdx.x;
    int b    = gid >> 4;
    int lane = gid & 15;
    if (b >= B) return;
    int u  = users[b];
    int it = N_USERS + items[b];
    float4 uv = ((const float4*)(h + (size_t)u  * DIM))[lane];
    float4 iv = ((const float4*)(h + (size_t)it * DIM))[lane];
    float4* up = (float4*)(u_acc  + (size_t)b * DIM) + lane;
    float4* ip = (float4*)(it_acc + (size_t)b * DIM) + lane;
    if (first) {
        *up = uv;
        *ip = iv;
    } else {
        float4 a = *up;
        a.x += uv.x; a.y += uv.y; a.z += uv.z; a.w += uv.w;
        *up = a;
        float4 c = *ip;
        c.x += iv.x; c.y += iv.y; c.z += iv.z; c.w += iv.w;
        *ip = c;
    }
}

__global__ void dot_kernel(const float* __restrict__ u_acc,
                           const float* __restrict__ it_acc,
                           float* __restrict__ out, int B) {
    int gid  = blockIdx.x * blockDim.x + threadIdx.x;
    int b    = gid >> 6;
    int lane = gid & 63;
    if (b >= B) return;
    float p = u_acc[(size_t)b * DIM + lane] * it_acc[(size_t)b * DIM + lane];
    #pragma unroll
    for (int off = 32; off > 0; off >>= 1)
        p += __shfl_down(p, off, 64);
    if (lane == 0) out[b] = p * (1.0f / 16.0f);
}

extern "C" void kernel_launch(void* const* d_in, const int* in_sizes, int n_in,
                              void* d_out, int out_size, void* d_ws, size_t ws_size,
                              hipStream_t stream) {
    const int*   users = (const int*)d_in[0];
    const int*   items = (const int*)d_in[1];
    const int*   erows = (const int*)d_in[2];
    const int*   ecols = (const int*)d_in[3];
    const float* evals = (const float*)d_in[4];
    const float* uemb  = (const float*)d_in[5];
    const float* iemb  = (const float*)d_in[6];
    const float* temb  = (const float*)d_in[7];
    float* out = (float*)d_out;

    const int n_edges = in_sizes[2];
    const int B       = in_sizes[0];

    const size_t hbytes  = (size_t)N_NODES * DIM * sizeof(float);        // 76.8 MB
    const size_t abytes  = (size_t)B * DIM * sizeof(float);              // 4.2 MB
    const size_t rpbytes = (((size_t)(N_NODES + 1) * 4 + 255) / 256) * 256;
    const size_t rcbytes = rpbytes;
    const size_t ecbytes = (size_t)n_edges * 4;

    char* ws = (char*)d_ws;
    size_t off = 0;
    float* hA      = (float*)(ws + off); off += hbytes;
    float* hB      = (float*)(ws + off); off += hbytes;
    float* u_acc   = (float*)(ws + off); off += abytes;
    float* it_acc  = (float*)(ws + off); off += abytes;
    int*   row_ptr = (int*)  (ws + off); off += rpbytes;
    int*   row_cnt = (int*)  (ws + off); off += rcbytes;
    int*   row_fil = (int*)  (ws + off); off += rcbytes;
    int*   csr_col = (int*)  (ws + off); off += ecbytes;
    float* csr_val = (float*)(ws + off); off += ecbytes;   // total ~207 MB

    dim3 blk(256);

    // ---- CSR build (once; reused for all 3 layers) ----
    hipMemsetAsync(row_cnt, 0, (size_t)N_NODES * 4, stream);
    hipMemsetAsync(row_fil, 0, (size_t)N_NODES * 4, stream);
    hist_kernel<<<2048, blk, 0, stream>>>(erows, row_cnt, n_edges);
    scan_kernel<<<1, SCAN_T, 0, stream>>>(row_cnt, row_ptr, N_NODES);
    scatter_kernel<<<2048, blk, 0, stream>>>(erows, ecols, evals, row_ptr, row_fil,
                                             csr_col, csr_val, n_edges);

    // ---- h0 = concat(user, item, topic) ----
    hipMemcpyAsync(hA,                                     uemb, (size_t)N_USERS  * DIM * 4, hipMemcpyDeviceToDevice, stream);
    hipMemcpyAsync(hA + (size_t)N_USERS * DIM,             iemb, (size_t)N_ITEMS  * DIM * 4, hipMemcpyDeviceToDevice, stream);
    hipMemcpyAsync(hA + (size_t)(N_USERS + N_ITEMS) * DIM, temb, (size_t)N_TOPICS * DIM * 4, hipMemcpyDeviceToDevice, stream);

    const int gblocks = (B * 16 + 255) / 256;
    gather_add_kernel<<<gblocks, blk, 0, stream>>>(hA, users, items, u_acc, it_acc, B, 1);

    const int sblocks = (int)(((long)N_NODES * 64 + 255) / 256);
    float* src = hA;
    float* dst = hB;
    for (int l = 0; l < 3; ++l) {
        spmv_csr_kernel<<<sblocks, blk, 0, stream>>>(row_ptr, csr_col, csr_val, src, dst);
        gather_add_kernel<<<gblocks, blk, 0, stream>>>(dst, users, items, u_acc, it_acc, B, 0);
        float* t = src; src = dst; dst = t;
    }

    dot_kernel<<<(B * 64 + 255) / 256, blk, 0, stream>>>(u_acc, it_acc, out, B);
}

// Round 3
// 1257.853 us; speedup vs baseline: 10.1739x; 1.6854x over previous
//
#include <hip/hip_runtime.h>

#define N_USERS  200000
#define N_ITEMS  100000
#define N_TOPICS 100
#define N_NODES  (N_USERS + N_ITEMS + N_TOPICS)
#define DIM      64
#define RB 256   // scan: number of chunks/blocks
#define RT 256   // scan: threads per block

// ---------- CSR build ----------

__global__ void hist_kernel(const int* __restrict__ rows, int* __restrict__ cnt,
                            int n_edges) {
    int stride = gridDim.x * blockDim.x;
    for (int e = blockIdx.x * blockDim.x + threadIdx.x; e < n_edges; e += stride)
        atomicAdd(&cnt[rows[e]], 1);
}

// Phase A: per-chunk sums (coalesced, device-wide).
__global__ void scan_reduce_kernel(const int* __restrict__ cnt,
                                   int* __restrict__ partial, int n) {
    __shared__ int s[RT];
    int tid   = threadIdx.x;
    int chunk = (n + RB - 1) / RB;
    int s0 = blockIdx.x * chunk;
    int s1 = min(n, s0 + chunk);
    int sum = 0;
    for (int i = s0 + tid; i < s1; i += RT) sum += cnt[i];
    s[tid] = sum;
    __syncthreads();
    for (int off = RT / 2; off > 0; off >>= 1) {
        if (tid < off) s[tid] += s[tid + off];
        __syncthreads();
    }
    if (tid == 0) partial[blockIdx.x] = s[0];
}

// Phase B: exclusive scan of the RB partials (single tiny block).
__global__ void scan_partials_kernel(int* __restrict__ partial) {
    __shared__ int s[RB];
    int tid = threadIdx.x;
    s[tid] = partial[tid];
    __syncthreads();
    for (int off = 1; off < RB; off <<= 1) {
        int v = (tid >= off) ? s[tid - off] : 0;
        __syncthreads();
        s[tid] += v;
        __syncthreads();
    }
    partial[tid] = tid ? s[tid - 1] : 0;   // exclusive
}

// Phase C: block-local scan + write row_ptr with chunk offset.
__global__ void scan_write_kernel(const int* __restrict__ cnt,
                                  const int* __restrict__ partial,
                                  int* __restrict__ row_ptr, int n) {
    __shared__ int tile[RT];
    __shared__ int carry;
    int tid   = threadIdx.x;
    int chunk = (n + RB - 1) / RB;
    int s0 = blockIdx.x * chunk;
    int s1 = min(n, s0 + chunk);
    if (tid == 0) carry = partial[blockIdx.x];
    __syncthreads();
    for (int base = s0; base < s1; base += RT) {
        int i = base + tid;
        int v = (i < s1) ? cnt[i] : 0;
        tile[tid] = v;
        __syncthreads();
        for (int off = 1; off < RT; off <<= 1) {
            int t = (tid >= off) ? tile[tid - off] : 0;
            __syncthreads();
            tile[tid] += t;
            __syncthreads();
        }
        if (i < s1) row_ptr[i] = carry + tile[tid] - v;   // exclusive
        __syncthreads();
        if (tid == RT - 1) carry += tile[RT - 1];
        __syncthreads();
    }
    if (blockIdx.x == RB - 1 && tid == 0) row_ptr[n] = carry;  // total = n_edges
}

// Interleaved (col, val-bits) CSR payload: one 8 B store per edge.
__global__ void scatter_kernel(const int* __restrict__ rows,
                               const int* __restrict__ cols,
                               const float* __restrict__ vals,
                               const int* __restrict__ row_ptr,
                               int* __restrict__ fill,
                               int2* __restrict__ csr_cv,
                               int n_edges) {
    int stride = gridDim.x * blockDim.x;
    for (int e = blockIdx.x * blockDim.x + threadIdx.x; e < n_edges; e += stride) {
        int r   = rows[e];
        int pos = row_ptr[r] + atomicAdd(&fill[r], 1);
        int2 cv;
        cv.x = cols[e];
        cv.y = __float_as_int(vals[e]);
        csr_cv[pos] = cv;
    }
}

// ---------- SpMV: 1 wave per row, 4 edges/iter, float4 per lane ----------
__global__ void spmv_csr_kernel(const int* __restrict__ row_ptr,
                                const int2* __restrict__ csr_cv,
                                const float* __restrict__ h_src,
                                float* __restrict__ h_dst) {
    int wid  = (int)(((long)blockIdx.x * blockDim.x + threadIdx.x) >> 6);
    int lane = threadIdx.x & 63;
    if (wid >= N_NODES) return;
    int g   = lane >> 4;     // edge slot 0..3 within iteration
    int l16 = lane & 15;     // float4 index within the 64-dim row
    int p0 = row_ptr[wid];
    int p1 = row_ptr[wid + 1];
    float4 acc = make_float4(0.f, 0.f, 0.f, 0.f);
    for (int base = p0; base < p1; base += 4) {
        int e = base + g;
        if (e < p1) {
            int2  cv = csr_cv[e];            // broadcast across the 16-lane group
            float v  = __int_as_float(cv.y);
            float4 s = ((const float4*)(h_src + (size_t)cv.x * DIM))[l16];
            acc.x += v * s.x;
            acc.y += v * s.y;
            acc.z += v * s.z;
            acc.w += v * s.w;
        }
    }
    // reduce across the 4 edge-groups (lanes with equal l16)
    acc.x += __shfl_xor(acc.x, 16, 64);  acc.x += __shfl_xor(acc.x, 32, 64);
    acc.y += __shfl_xor(acc.y, 16, 64);  acc.y += __shfl_xor(acc.y, 32, 64);
    acc.z += __shfl_xor(acc.z, 16, 64);  acc.z += __shfl_xor(acc.z, 32, 64);
    acc.w += __shfl_xor(acc.w, 16, 64);  acc.w += __shfl_xor(acc.w, 32, 64);
    if (lane < 16)
        ((float4*)(h_dst + (size_t)wid * DIM))[l16] = acc;
}

// ---------- batch-row accumulation + readout ----------

__global__ void gather_add_kernel(const float* __restrict__ h,
                                  const int* __restrict__ users,
                                  const int* __restrict__ items,
                                  float* __restrict__ u_acc,
                                  float* __restrict__ it_acc,
                                  int B, int first) {
    int gid  = blockIdx.x * blockDim.x + threadIdx.x;
    int b    = gid >> 4;
    int lane = gid & 15;
    if (b >= B) return;
    int u  = users[b];
    int it = N_USERS + items[b];
    float4 uv = ((const float4*)(h + (size_t)u  * DIM))[lane];
    float4 iv = ((const float4*)(h + (size_t)it * DIM))[lane];
    float4* up = (float4*)(u_acc  + (size_t)b * DIM) + lane;
    float4* ip = (float4*)(it_acc + (size_t)b * DIM) + lane;
    if (first) {
        *up = uv;
        *ip = iv;
    } else {
        float4 a = *up;
        a.x += uv.x; a.y += uv.y; a.z += uv.z; a.w += uv.w;
        *up = a;
        float4 c = *ip;
        c.x += iv.x; c.y += iv.y; c.z += iv.z; c.w += iv.w;
        *ip = c;
    }
}

__global__ void dot_kernel(const float* __restrict__ u_acc,
                           const float* __restrict__ it_acc,
                           float* __restrict__ out, int B) {
    int gid  = blockIdx.x * blockDim.x + threadIdx.x;
    int b    = gid >> 6;
    int lane = gid & 63;
    if (b >= B) return;
    float p = u_acc[(size_t)b * DIM + lane] * it_acc[(size_t)b * DIM + lane];
    #pragma unroll
    for (int off = 32; off > 0; off >>= 1)
        p += __shfl_down(p, off, 64);
    if (lane == 0) out[b] = p * (1.0f / 16.0f);
}

extern "C" void kernel_launch(void* const* d_in, const int* in_sizes, int n_in,
                              void* d_out, int out_size, void* d_ws, size_t ws_size,
                              hipStream_t stream) {
    const int*   users = (const int*)d_in[0];
    const int*   items = (const int*)d_in[1];
    const int*   erows = (const int*)d_in[2];
    const int*   ecols = (const int*)d_in[3];
    const float* evals = (const float*)d_in[4];
    const float* uemb  = (const float*)d_in[5];
    const float* iemb  = (const float*)d_in[6];
    const float* temb  = (const float*)d_in[7];
    float* out = (float*)d_out;

    const int n_edges = in_sizes[2];
    const int B       = in_sizes[0];

    const size_t hbytes  = (size_t)N_NODES * DIM * sizeof(float);        // 76.8 MB
    const size_t abytes  = (size_t)B * DIM * sizeof(float);              // 4.2 MB
    const size_t rpbytes = (((size_t)(N_NODES + 1) * 4 + 255) / 256) * 256;
    const size_t cvbytes = (size_t)n_edges * 8;

    char* ws = (char*)d_ws;
    size_t off = 0;
    float* hA      = (float*)(ws + off); off += hbytes;
    float* hB      = (float*)(ws + off); off += hbytes;
    float* u_acc   = (float*)(ws + off); off += abytes;
    float* it_acc  = (float*)(ws + off); off += abytes;
    int*   row_ptr = (int*)  (ws + off); off += rpbytes;
    int*   row_cnt = (int*)  (ws + off); off += rpbytes;
    int*   row_fil = (int*)  (ws + off); off += rpbytes;
    int*   partial = (int*)  (ws + off); off += 4096;
    int2*  csr_cv  = (int2*) (ws + off); off += cvbytes;   // total ~207 MB

    dim3 blk(256);

    // ---- CSR build (once; reused for all 3 layers) ----
    hipMemsetAsync(row_cnt, 0, (size_t)N_NODES * 4, stream);
    hipMemsetAsync(row_fil, 0, (size_t)N_NODES * 4, stream);
    hist_kernel<<<2048, blk, 0, stream>>>(erows, row_cnt, n_edges);
    scan_reduce_kernel  <<<RB, RT, 0, stream>>>(row_cnt, partial, N_NODES);
    scan_partials_kernel<<<1,  RB, 0, stream>>>(partial);
    scan_write_kernel   <<<RB, RT, 0, stream>>>(row_cnt, partial, row_ptr, N_NODES);
    scatter_kernel<<<2048, blk, 0, stream>>>(erows, ecols, evals, row_ptr, row_fil,
                                             csr_cv, n_edges);

    // ---- h0 = concat(user, item, topic) ----
    hipMemcpyAsync(hA,                                     uemb, (size_t)N_USERS  * DIM * 4, hipMemcpyDeviceToDevice, stream);
    hipMemcpyAsync(hA + (size_t)N_USERS * DIM,             iemb, (size_t)N_ITEMS  * DIM * 4, hipMemcpyDeviceToDevice, stream);
    hipMemcpyAsync(hA + (size_t)(N_USERS + N_ITEMS) * DIM, temb, (size_t)N_TOPICS * DIM * 4, hipMemcpyDeviceToDevice, stream);

    const int gblocks = (B * 16 + 255) / 256;
    gather_add_kernel<<<gblocks, blk, 0, stream>>>(hA, users, items, u_acc, it_acc, B, 1);

    const int sblocks = (int)(((long)N_NODES * 64 + 255) / 256);
    float* src = hA;
    float* dst = hB;
    for (int l = 0; l < 3; ++l) {
        spmv_csr_kernel<<<sblocks, blk, 0, stream>>>(row_ptr, csr_cv, src, dst);
        gather_add_kernel<<<gblocks, blk, 0, stream>>>(dst, users, items, u_acc, it_acc, B, 0);
        float* t = src; src = dst; dst = t;
    }

    dot_kernel<<<(B * 64 + 255) / 256, blk, 0, stream>>>(u_acc, it_acc, out, B);
}